// Round 6
// baseline (681.146 us; speedup 1.0000x reference)
//
#include <hip/hip_runtime.h>

typedef unsigned short u16;
typedef __attribute__((ext_vector_type(8))) short short8;
typedef __attribute__((ext_vector_type(4))) float f32x4;

#define MFMA16(a, b, c) __builtin_amdgcn_mfma_f32_16x16x32_bf16((a), (b), (c), 0, 0, 0)

// ---- workspace layout (bytes) ---- total ~1.39 MB (validated by r3's correct output)
#define OFF_BIAS 0            // fp32 [12][64][64]      = 196608
#define OFF_SCALES 196608     // fp32 [12]              (64 B slot)
#define OFF_RPB 196672        // fp32 [225][12]         = 10800
#define OFF_QKVT 207616       // bf16 [1152][384]       = 884736
#define OFF_PROJT 1092352     // bf16 [384][384]        = 294912  (end 1387264)

__device__ __forceinline__ float bf2f(u16 u) { return __uint_as_float(((unsigned)u) << 16); }
__device__ __forceinline__ u16 f2bf(float f) {
  unsigned x = __float_as_uint(f);
  return (u16)((x + 0x7fffu + ((x >> 16) & 1u)) >> 16);  // RNE, finite values only
}
// 8 consecutive fp32 -> bf16x8 fragment
__device__ __forceinline__ short8 ld8f(const float* __restrict__ f) {
  short8 r;
#pragma unroll
  for (int j = 0; j < 8; ++j) r[j] = (short)f2bf(f[j]);
  return r;
}

// ---- prep: transpose weights into bf16 + head scales ----
__global__ __launch_bounds__(256) void prep_misc(const float* __restrict__ qkv_w,
                                                 const float* __restrict__ proj_w,
                                                 const float* __restrict__ logit_scale,
                                                 u16* __restrict__ qkvT, u16* __restrict__ projT,
                                                 float* __restrict__ scales) {
  int idx = blockIdx.x * 256 + threadIdx.x;
  if (idx < 442368) {
    int r = idx / 1152, c = idx % 1152;
    qkvT[c * 384 + r] = f2bf(qkv_w[idx]);
  } else if (idx < 442368 + 147456) {
    int k = idx - 442368;
    int r = k / 384, c = k % 384;
    projT[c * 384 + r] = f2bf(proj_w[k]);
  } else if (idx < 442368 + 147456 + 12) {
    int h = idx - (442368 + 147456);
    scales[h] = __expf(fminf(logit_scale[h], 4.6051702f));  // log(1/0.01)
  }
}

// ---- prep: CPB MLP  rpb[t][h] = relu(tab@w1+b1)@w2+b2 ----
__global__ __launch_bounds__(256) void prep_cpb(const float* __restrict__ tab, const float* __restrict__ w1,
                                                const float* __restrict__ b1, const float* __restrict__ w2,
                                                const float* __restrict__ b2, float* __restrict__ rpb) {
  int t = threadIdx.x;
  if (t >= 225) return;
  float t0 = tab[2 * t], t1 = tab[2 * t + 1];
  float acc[12];
#pragma unroll
  for (int h = 0; h < 12; ++h) acc[h] = 0.f;
  for (int j = 0; j < 512; ++j) {
    float hv = fmaxf(t0 * w1[j] + t1 * w1[512 + j] + b1[j], 0.f);
#pragma unroll
    for (int h = 0; h < 12; ++h) acc[h] += hv * w2[j * 12 + h];
  }
#pragma unroll
  for (int h = 0; h < 12; ++h) rpb[t * 12 + h] = acc[h] + b2[h];
}

// ---- prep: gather 16*sigmoid(rpb) into dense (12,64,64) fp32 ----
__global__ __launch_bounds__(256) void prep_bias(const int* __restrict__ rpb_idx,
                                                 const float* __restrict__ rpb,
                                                 float* __restrict__ bias) {
  int p = blockIdx.x * 256 + threadIdx.x;
  if (p >= 4096) return;
  int t = rpb_idx[p];
#pragma unroll
  for (int h = 0; h < 12; ++h) bias[h * 4096 + p] = 16.f / (1.f + __expf(-rpb[t * 12 + h]));
}

// ---- fused window attention: one block = one window, wave w handles heads 3w..3w+2 ----
// Writes pre-projection activations (fp32) into d_out; proj_kernel then runs in place.
__global__ __launch_bounds__(256) void attn_kernel(const float* __restrict__ x, const float* __restrict__ mask,
                                                   const u16* __restrict__ qkvT,
                                                   const float* __restrict__ scales,
                                                   const float* __restrict__ bias,
                                                   float* __restrict__ attnout) {
  __shared__ u16 wsc_all[4][6144];  // 12 KB wave-private scratch each
  const int tid = threadIdx.x;
  const int wave = tid >> 6, lane = tid & 63;
  const int q16 = lane >> 4, c16 = lane & 15;
  const int widx = blockIdx.x, wm = widx & 63;
  u16* qs = wsc_all[wave];          // [64][32] bf16 (normalized, scaled q)
  u16* ks = wsc_all[wave] + 2048;   // [64][32]
  u16* ps = wsc_all[wave];          // [64][64] probs (overlays qs+ks exactly)
  u16* vst = wsc_all[wave] + 4096;  // [32 dim][64 tok]  (transposed v)
  const float* xw = x + (long)widx * 24576;
  const f32x4 fzero = {0.f, 0.f, 0.f, 0.f};

  for (int hh = 0; hh < 3; ++hh) {
    const int h = wave * 3 + hh;
    const float sc = scales[h];
    // ---- Phase A: q,k,v = x_w @ W  (M=64,N=32 each, K=384), MFMA ----
    f32x4 qa[4][2], ka[4][2], va[4][2];
#pragma unroll
    for (int i = 0; i < 4; ++i)
#pragma unroll
      for (int j = 0; j < 2; ++j) {
        qa[i][j] = fzero; ka[i][j] = fzero; va[i][j] = fzero;
      }
#pragma unroll 2
    for (int t = 0; t < 12; ++t) {
      const int k0 = t * 32 + q16 * 8;
      short8 af[4];
#pragma unroll
      for (int i = 0; i < 4; ++i)
        af[i] = ld8f(xw + (c16 + 16 * i) * 384 + k0);
#pragma unroll
      for (int jn = 0; jn < 2; ++jn) {
        const int col = h * 32 + 16 * jn + c16;
        short8 bq = *reinterpret_cast<const short8*>(qkvT + col * 384 + k0);
        short8 bk = *reinterpret_cast<const short8*>(qkvT + (col + 384) * 384 + k0);
        short8 bv = *reinterpret_cast<const short8*>(qkvT + (col + 768) * 384 + k0);
#pragma unroll
        for (int i = 0; i < 4; ++i) {
          qa[i][jn] = MFMA16(af[i], bq, qa[i][jn]);
          ka[i][jn] = MFMA16(af[i], bk, ka[i][jn]);
          va[i][jn] = MFMA16(af[i], bv, va[i][jn]);
        }
      }
    }
    // ---- Phase B: row-normalize q (×scale) and k; stage, v transposed ----
    // C/D layout (HW-verified m89/m91): col = lane&15, row = (lane>>4)*4 + reg
#pragma unroll
    for (int i = 0; i < 4; ++i) {
#pragma unroll
      for (int r = 0; r < 4; ++r) {
        const int row = 16 * i + 4 * q16 + r;
        float sq = qa[i][0][r] * qa[i][0][r] + qa[i][1][r] * qa[i][1][r];
        float sk = ka[i][0][r] * ka[i][0][r] + ka[i][1][r] * ka[i][1][r];
#pragma unroll
        for (int off = 1; off < 16; off <<= 1) {
          sq += __shfl_xor(sq, off);
          sk += __shfl_xor(sk, off);
        }
        const float rq = rsqrtf(fmaxf(sq, 1e-12f)) * sc;
        const float rk = rsqrtf(fmaxf(sk, 1e-12f));
#pragma unroll
        for (int jn = 0; jn < 2; ++jn) {
          const int col = 16 * jn + c16;
          qs[row * 32 + col] = f2bf(qa[i][jn][r] * rq);
          ks[row * 32 + col] = f2bf(ka[i][jn][r] * rk);
          vst[col * 64 + row] = f2bf(va[i][jn][r]);
        }
      }
    }
    __syncthreads();
    // ---- Phase C: S = q @ k^T  (64x64, K=32 -> 1 MFMA per tile) ----
    short8 aq[4], bk4[4];
#pragma unroll
    for (int i = 0; i < 4; ++i)
      aq[i] = *reinterpret_cast<const short8*>(qs + (c16 + 16 * i) * 32 + q16 * 8);
#pragma unroll
    for (int j = 0; j < 4; ++j)
      bk4[j] = *reinterpret_cast<const short8*>(ks + (c16 + 16 * j) * 32 + q16 * 8);
    f32x4 sacc[4][4];
#pragma unroll
    for (int i = 0; i < 4; ++i)
#pragma unroll
      for (int j = 0; j < 4; ++j) sacc[i][j] = MFMA16(aq[i], bk4[j], fzero);
    // ---- Phase D: + bias + mask, softmax over keys ----
    const float* bh = bias + h * 4096;
    const float* mw = mask + (long)wm * 4096;
#pragma unroll
    for (int i = 0; i < 4; ++i)
#pragma unroll
      for (int j = 0; j < 4; ++j) {
        const int col = 16 * j + c16;
#pragma unroll
        for (int r = 0; r < 4; ++r) {
          const int row = 16 * i + 4 * q16 + r;
          sacc[i][j][r] += bh[row * 64 + col] + mw[row * 64 + col];
        }
      }
    __syncthreads();  // qs/ks fragment reads drained before ps overlays them
#pragma unroll
    for (int i = 0; i < 4; ++i) {
#pragma unroll
      for (int r = 0; r < 4; ++r) {
        float m = sacc[i][0][r];
#pragma unroll
        for (int j = 1; j < 4; ++j) m = fmaxf(m, sacc[i][j][r]);
#pragma unroll
        for (int off = 1; off < 16; off <<= 1) m = fmaxf(m, __shfl_xor(m, off));
        float s = 0.f, e[4];
#pragma unroll
        for (int j = 0; j < 4; ++j) {
          e[j] = __expf(sacc[i][j][r] - m);
          s += e[j];
        }
#pragma unroll
        for (int off = 1; off < 16; off <<= 1) s += __shfl_xor(s, off);
        const float inv = 1.f / s;
        const int row = 16 * i + 4 * q16 + r;
#pragma unroll
        for (int j = 0; j < 4; ++j) ps[row * 64 + 16 * j + c16] = f2bf(e[j] * inv);
      }
    }
    __syncthreads();
    // ---- Phase E: O = P @ V  (M=64,N=32,K=64) ----
    f32x4 oa[4][2];
#pragma unroll
    for (int i = 0; i < 4; ++i) {
      oa[i][0] = fzero;
      oa[i][1] = fzero;
    }
#pragma unroll
    for (int kt = 0; kt < 2; ++kt) {
      short8 ap[4], bv2[2];
#pragma unroll
      for (int i = 0; i < 4; ++i)
        ap[i] = *reinterpret_cast<const short8*>(ps + (c16 + 16 * i) * 64 + kt * 32 + q16 * 8);
#pragma unroll
      for (int jn = 0; jn < 2; ++jn)
        bv2[jn] = *reinterpret_cast<const short8*>(vst + (16 * jn + c16) * 64 + kt * 32 + q16 * 8);
#pragma unroll
      for (int i = 0; i < 4; ++i)
#pragma unroll
        for (int jn = 0; jn < 2; ++jn) oa[i][jn] = MFMA16(ap[i], bv2[jn], oa[i][jn]);
    }
    // ---- Phase F: write attention output (pre-proj, fp32) to d_out staging ----
    float* ob = attnout + (long)widx * 24576 + h * 32;
#pragma unroll
    for (int i = 0; i < 4; ++i)
#pragma unroll
      for (int jn = 0; jn < 2; ++jn)
#pragma unroll
        for (int r = 0; r < 4; ++r) {
          const int tok = 16 * i + 4 * q16 + r;
          ob[(long)tok * 384 + 16 * jn + c16] = oa[i][jn][r];
        }
    __syncthreads();
  }
}

// ---- output projection, IN PLACE on d_out (fp32): io = io @ proj_w + proj_b ----
// Block b stages rows [64b,64b+64) into LDS (as bf16), syncs, overwrites exactly those rows.
__global__ __launch_bounds__(256) void proj_kernel(float* io, const u16* __restrict__ projT,
                                                   const float* __restrict__ proj_b) {
  __shared__ u16 as_[64 * 384];
  const int tid = threadIdx.x;
  const int wave = tid >> 6, lane = tid & 63;
  const int q16 = lane >> 4, c16 = lane & 15;
  const int blk = blockIdx.x;
  {
    const float* src = io + (long)blk * 24576;
    // 24576 floats / 256 threads = 96 each; float4-vectorized: 24 float4 each
    const float4* s4 = reinterpret_cast<const float4*>(src);
#pragma unroll
    for (int it = 0; it < 24; ++it) {
      const float4 v = s4[it * 256 + tid];
      const int e = (it * 256 + tid) * 4;
      as_[e + 0] = f2bf(v.x);
      as_[e + 1] = f2bf(v.y);
      as_[e + 2] = f2bf(v.z);
      as_[e + 3] = f2bf(v.w);
    }
  }
  __syncthreads();
  const f32x4 fzero = {0.f, 0.f, 0.f, 0.f};
  f32x4 acc[4][6];
#pragma unroll
  for (int i = 0; i < 4; ++i)
#pragma unroll
    for (int jn = 0; jn < 6; ++jn) acc[i][jn] = fzero;
#pragma unroll 2
  for (int t = 0; t < 12; ++t) {
    const int k0 = t * 32 + q16 * 8;
    short8 af[4];
#pragma unroll
    for (int i = 0; i < 4; ++i)
      af[i] = *reinterpret_cast<const short8*>(as_ + (c16 + 16 * i) * 384 + k0);
#pragma unroll
    for (int jn = 0; jn < 6; ++jn) {
      const int n = wave * 96 + 16 * jn + c16;
      short8 bf_ = *reinterpret_cast<const short8*>(projT + n * 384 + k0);
#pragma unroll
      for (int i = 0; i < 4; ++i) acc[i][jn] = MFMA16(af[i], bf_, acc[i][jn]);
    }
  }
  float* ob = io + (long)blk * 24576;
#pragma unroll
  for (int jn = 0; jn < 6; ++jn) {
    const int n = wave * 96 + 16 * jn + c16;
    const float bv = proj_b[n];
#pragma unroll
    for (int i = 0; i < 4; ++i)
#pragma unroll
      for (int r = 0; r < 4; ++r) {
        const int row = 16 * i + 4 * q16 + r;
        ob[(long)row * 384 + n] = acc[i][jn][r] + bv;
      }
  }
}

extern "C" void kernel_launch(void* const* d_in, const int* in_sizes, int n_in, void* d_out,
                              int out_size, void* d_ws, size_t ws_size, hipStream_t stream) {
  const float* x = (const float*)d_in[0];
  const float* mask = (const float*)d_in[1];
  const float* qkv_w = (const float*)d_in[2];
  const float* proj_w = (const float*)d_in[3];
  const float* proj_b = (const float*)d_in[4];
  const float* cpb_w1 = (const float*)d_in[5];
  const float* cpb_b1 = (const float*)d_in[6];
  const float* cpb_w2 = (const float*)d_in[7];
  const float* cpb_b2 = (const float*)d_in[8];
  const float* logit_scale = (const float*)d_in[9];
  const float* rpb_table = (const float*)d_in[10];
  const int* rpb_idx = (const int*)d_in[11];

  char* ws = (char*)d_ws;
  float* bias = (float*)(ws + OFF_BIAS);
  float* scales = (float*)(ws + OFF_SCALES);
  float* rpb = (float*)(ws + OFF_RPB);
  u16* qkvT = (u16*)(ws + OFF_QKVT);
  u16* projT = (u16*)(ws + OFF_PROJT);
  float* staging = (float*)d_out;  // pre-projection activations live in d_out (fp32)

  prep_misc<<<2305, 256, 0, stream>>>(qkv_w, proj_w, logit_scale, qkvT, projT, scales);
  prep_cpb<<<1, 256, 0, stream>>>(rpb_table, cpb_w1, cpb_b1, cpb_w2, cpb_b2, rpb);
  prep_bias<<<16, 256, 0, stream>>>(rpb_idx, rpb, bias);
  attn_kernel<<<1024, 256, 0, stream>>>(x, mask, qkvT, scales, bias, staging);
  proj_kernel<<<1024, 256, 0, stream>>>(staging, projT, proj_b);
}